// Round 9
// baseline (132.165 us; speedup 1.0000x reference)
//
#include <hip/hip_runtime.h>
#include <hip/hip_bf16.h>

// QKVAttentionLegacy: qkv (4,3072,1024) fp32, 16 heads, ch=64.
// R17 = paired-tile windows: each barrier window processes TWO s-tiles
// (a=2p, b=2p+1). Straight-line body gives the compiler SM(a)||QK(b) and
// SM(b)||PV(a) overlap with NO wave-dependent branches (R16's spill trap) and
// NO cross-window P carry. Barriers: 16 -> 8.
//  - pair-buf double buffering: window p reads buf (p&1), stages pair p+1 into
//    buf ((p+1)&1). Any buf's reads (window p-1) and writes (window p) are
//    separated by the end-of-(p-1) lgkmcnt(0)+barrier. PV reads same-window
//    bufs only -> no triple-buffer, no PV tail after the loop.
//  - Q loaded global->regs (verified R12/R13); no q_s; LDS = 64KB exactly
//    (4 pair-bufs x 16KB), 2 blocks/CU = 128KB <= 160KB.
//  - raw barrier {lgkmcnt(0); s_barrier} (R15-verified; vmem stays in flight),
//    both next-tile load sets issued at window top (full-window slack).
// Core math identical to R11/R15 (verified): 32x32x16 MFMAs; sigma-permuted K
// rows (swap bits 2<->3) -> PV B-frag = pk(St[2d],St[2d+1]) identical reg
// indices both lane halves (no permlane, no LDS for P); kap bank swizzles
// (verified floors); s-split epilogue via retired LDS.
// Grid 512 (8 t-tiles x 64 bh, bh fastest -> XCD), 512 threads, 2 blocks/CU.

typedef __bf16 bf16_8 __attribute__((ext_vector_type(8)));
typedef __bf16 bf16_4 __attribute__((ext_vector_type(4)));
typedef float floatx4 __attribute__((ext_vector_type(4)));
typedef float floatx16 __attribute__((ext_vector_type(16)));

#define NTHREADS 512
#define STR 64               // bf16 elems per LDS row (128 B, swizzle not pad)
#define NPAIRS 8

#if __has_builtin(__builtin_amdgcn_exp2f)
#define EXP2(x) __builtin_amdgcn_exp2f(x)
#else
#define EXP2(x) exp2f(x)
#endif
// (1/8)*log2(e): qk scale + exp->exp2, folded into Q load (one bf16 rounding).
#define QSCALE 0.18033688011112042f

// LDS: kp0 @0 | kp1 @16384 | vp0 @32768 | vp1 @49152  (each pair-buf 16KB =
// two 8KB tiles: sub-tile t at +t*8192). Epilogue: xo 32KB @0 (kp0/kp1),
// xl @32768 (vp0; final window reads vp1 only).
#define LDS_BYTES 65536

#define ZERO16 (floatx16){0.f,0.f,0.f,0.f,0.f,0.f,0.f,0.f,0.f,0.f,0.f,0.f,0.f,0.f,0.f,0.f}

// Raw barrier: LDS visibility only; vmem loads stay outstanding across it.
#define BAR() do {                                          \
    asm volatile("s_waitcnt lgkmcnt(0)" ::: "memory");      \
    __builtin_amdgcn_s_barrier();                           \
    __builtin_amdgcn_sched_barrier(0);                      \
} while (0)

__device__ __forceinline__ int kap(int row) { return ((row >> 1) + (row >> 4)) & 7; }
// swap bits 2<->3 (keep 0,1,4,5); self-inverse. K s-row -> LDS row relabeling.
__device__ __forceinline__ int sigma_row(int s) {
    return (s & 0x33) | ((s & 4) << 1) | ((s & 8) >> 1);
}

__device__ __forceinline__ unsigned pk_bf16(float a, float b) {
    unsigned r;
    asm("v_cvt_pk_bf16_f32 %0, %1, %2" : "=v"(r) : "v"(a), "v"(b));
    return r;
}

union U8 { unsigned u[4]; bf16_8 v; };
union U4 { unsigned u[2]; bf16_4 v; };

__device__ __forceinline__ void write_k(__bf16* kn, const float4* r, int si, int sG) {
    #pragma unroll
    for (int rr = 0; rr < 4; ++rr) {
        int srow = si * 4 + rr;
        int m = sigma_row(srow);          // permuted LDS row
        U4 w;
        w.u[0] = pk_bf16(((const float*)&r[0])[rr], ((const float*)&r[1])[rr]);
        w.u[1] = pk_bf16(((const float*)&r[2])[rr], ((const float*)&r[3])[rr]);
        *(bf16_4*)&kn[m * STR + ((sG ^ (kap(m) << 1)) << 2)] = w.v;
    }
}
__device__ __forceinline__ void write_v(__bf16* vn, const float4* r, int si, int c0) {
    #pragma unroll
    for (int jj = 0; jj < 4; ++jj) {
        int c = c0 + jj;
        U4 w;
        w.u[0] = pk_bf16(r[jj].x, r[jj].y);
        w.u[1] = pk_bf16(r[jj].z, r[jj].w);
        *(bf16_4*)&vn[c * STR + ((si ^ (kap(c) << 1)) << 2)] = w.v;
    }
}

__global__ __launch_bounds__(NTHREADS, 4)
void attn_kernel(const float* __restrict__ qkv, float* __restrict__ out) {
    __shared__ char smem[LDS_BYTES];
    __bf16* kp0 = (__bf16*)smem;
    __bf16* kp1 = (__bf16*)(smem + 16384);
    __bf16* vp0 = (__bf16*)(smem + 32768);
    __bf16* vp1 = (__bf16*)(smem + 49152);

    const int tid  = threadIdx.x;
    const int wave = tid >> 6;
    const int lane = tid & 63;
    const int hv   = lane >> 5;          // lane half (k-octet select)
    const int l31  = lane & 31;
    const int g    = wave >> 1;          // t-group: rows [32g, 32g+32), g in 0..3
    const int sh   = wave & 1;           // s-half: [32sh, 32sh+32) of each tile

    const int bx = blockIdx.x;           // 512 = 8 t-tiles * 64 bh (bh fastest -> XCD)
    const int bh = bx & 63;
    const int t0 = (bx >> 6) << 7;       // *128

    const float* qg = qkv + (size_t)bh * 196608;
    const float* kg = qg + 65536;
    const float* vg = qg + 131072;

    // staging split: waves 0-3 stage K, waves 4-7 stage V
    const int sv = tid >> 8;
    const int st = tid & 255;
    const int si = st & 15;
    const int sG = st >> 4;
    const int c0 = sG << 2;
    const float* gsrc = sv ? vg : kg;

    // ---- Q B-frags straight from global (coalesced over t), scaled+packed ----
    // qf[kc] element e maps to c = 16*kc + 8*hv + e at t = t0 + 32g + l31.
    bf16_8 qf[4];
    {
        const int tq = t0 + g * 32 + l31;
        #pragma unroll
        for (int kc = 0; kc < 4; ++kc) {
            U8 w;
            #pragma unroll
            for (int d = 0; d < 4; ++d) {
                float f0 = qg[(16 * kc + 8 * hv + 2 * d) * 1024 + tq] * QSCALE;
                float f1 = qg[(16 * kc + 8 * hv + 2 * d + 1) * 1024 + tq] * QSCALE;
                w.u[d] = pk_bf16(f0, f1);
            }
            qf[kc] = w.v;
        }
    }

    // ---- stage pair 0 (tiles 0,1) into buf 0 ----
    {
        #pragma unroll
        for (int t = 0; t < 2; ++t) {
            float4 r4[4];
            #pragma unroll
            for (int jj = 0; jj < 4; ++jj)
                r4[jj] = *(const float4*)(gsrc + (c0 + jj) * 1024 + t * 64 + si * 4);
            if (!sv) write_k(kp0 + t * 4096, r4, si, sG);
            else     write_v(vp0 + t * 4096, r4, si, c0);
        }
    }
    __syncthreads();                     // prologue barrier (once; full drain fine)

    floatx16 O0 = ZERO16, O1 = ZERO16;   // c-tiles [0,32), [32,64); partial over sh
    float l = 0.f;

    const int krow = sh * 32 + l31;      // K A-frag LDS row (sigma applied on write)
    const int kx   = kap(krow);
    const int vx0  = kap(l31);
    const int vx1  = kap(32 + l31);

    for (int p = 0; p < NPAIRS; ++p) {
        const __bf16* kb = (p & 1) ? kp1 : kp0;      // this window's pair-bufs
        const __bf16* vb = (p & 1) ? vp1 : vp0;
        __bf16* kn = (p & 1) ? kp0 : kp1;            // next pair staged here
        __bf16* vn = (p & 1) ? vp0 : vp1;

        // ---- issue both next-pair load sets at window top (full-window slack)
        float4 rA[4], rB[4];
        if (p < NPAIRS - 1) {
            const int s0n = (2 * p + 2) * 64;
            #pragma unroll
            for (int jj = 0; jj < 4; ++jj)
                rA[jj] = *(const float4*)(gsrc + (c0 + jj) * 1024 + s0n + si * 4);
            #pragma unroll
            for (int jj = 0; jj < 4; ++jj)
                rB[jj] = *(const float4*)(gsrc + (c0 + jj) * 1024 + s0n + 64 + si * 4);
        }

        // ---- QK(a): sub-tile 0 ----
        floatx16 St = ZERO16;
        #pragma unroll
        for (int kc = 0; kc < 4; ++kc) {
            bf16_8 kf = *(const bf16_8*)&kb[krow * STR + ((((kc << 1) | hv) ^ kx) << 3)];
            St = __builtin_amdgcn_mfma_f32_32x32x16_bf16(kf, qf[kc], St, 0, 0, 0);
        }
        // ---- SM(a) -> pfa ----
        U8 wa0, wa1;
        #pragma unroll
        for (int d = 0; d < 4; ++d) {
            float pa = EXP2(St[2 * d]);
            float pb = EXP2(St[2 * d + 1]);
            float pc = EXP2(St[8 + 2 * d]);
            float pd = EXP2(St[8 + 2 * d + 1]);
            l += (pa + pb) + (pc + pd);
            wa0.u[d] = pk_bf16(pa, pb);
            wa1.u[d] = pk_bf16(pc, pd);
        }
        bf16_8 pfa0 = wa0.v, pfa1 = wa1.v;

        // ---- stage n1 (tile 2p+2) into next bufs (rA has ~QK+SM of slack) ----
        if (p < NPAIRS - 1) {
            if (!sv) write_k(kn, rA, si, sG);
            else     write_v(vn, rA, si, c0);
        }

        // ---- QK(b): sub-tile 1 ----
        floatx16 Su = ZERO16;
        #pragma unroll
        for (int kc = 0; kc < 4; ++kc) {
            bf16_8 kf = *(const bf16_8*)&kb[4096 + krow * STR + ((((kc << 1) | hv) ^ kx) << 3)];
            Su = __builtin_amdgcn_mfma_f32_32x32x16_bf16(kf, qf[kc], Su, 0, 0, 0);
        }
        // ---- SM(b) (VALU) || PV(a) (LDS+MFMA): independent, straight-line ----
        U8 wb0, wb1;
        #pragma unroll
        for (int d = 0; d < 4; ++d) {
            float pa = EXP2(Su[2 * d]);
            float pb = EXP2(Su[2 * d + 1]);
            float pc = EXP2(Su[8 + 2 * d]);
            float pd = EXP2(Su[8 + 2 * d + 1]);
            l += (pa + pb) + (pc + pd);
            wb0.u[d] = pk_bf16(pa, pb);
            wb1.u[d] = pk_bf16(pc, pd);
        }
        bf16_8 pfb0 = wb0.v, pfb1 = wb1.v;
        {   // PV(a): V sub-tile 0
            const __bf16* vp = vb;
            {
                int vrow = l31;
                bf16_8 vfa = *(const bf16_8*)&vp[vrow * STR + ((((sh << 2) | hv) ^ vx0) << 3)];
                O0 = __builtin_amdgcn_mfma_f32_32x32x16_bf16(vfa, pfa0, O0, 0, 0, 0);
                bf16_8 vfb = *(const bf16_8*)&vp[vrow * STR + ((((sh << 2) | 2 | hv) ^ vx0) << 3)];
                O0 = __builtin_amdgcn_mfma_f32_32x32x16_bf16(vfb, pfa1, O0, 0, 0, 0);
            }
            {
                int vrow = 32 + l31;
                bf16_8 vfa = *(const bf16_8*)&vp[vrow * STR + ((((sh << 2) | hv) ^ vx1) << 3)];
                O1 = __builtin_amdgcn_mfma_f32_32x32x16_bf16(vfa, pfa0, O1, 0, 0, 0);
                bf16_8 vfb = *(const bf16_8*)&vp[vrow * STR + ((((sh << 2) | 2 | hv) ^ vx1) << 3)];
                O1 = __builtin_amdgcn_mfma_f32_32x32x16_bf16(vfb, pfa1, O1, 0, 0, 0);
            }
        }

        // ---- stage n2 (tile 2p+3) ----
        if (p < NPAIRS - 1) {
            if (!sv) write_k(kn + 4096, rB, si, sG);
            else     write_v(vn + 4096, rB, si, c0);
        }

        // ---- PV(b): V sub-tile 1 ----
        {
            const __bf16* vp = vb + 4096;
            {
                int vrow = l31;
                bf16_8 vfa = *(const bf16_8*)&vp[vrow * STR + ((((sh << 2) | hv) ^ vx0) << 3)];
                O0 = __builtin_amdgcn_mfma_f32_32x32x16_bf16(vfa, pfb0, O0, 0, 0, 0);
                bf16_8 vfb = *(const bf16_8*)&vp[vrow * STR + ((((sh << 2) | 2 | hv) ^ vx0) << 3)];
                O0 = __builtin_amdgcn_mfma_f32_32x32x16_bf16(vfb, pfb1, O0, 0, 0, 0);
            }
            {
                int vrow = 32 + l31;
                bf16_8 vfa = *(const bf16_8*)&vp[vrow * STR + ((((sh << 2) | hv) ^ vx1) << 3)];
                O1 = __builtin_amdgcn_mfma_f32_32x32x16_bf16(vfa, pfb0, O1, 0, 0, 0);
                bf16_8 vfb = *(const bf16_8*)&vp[vrow * STR + ((((sh << 2) | 2 | hv) ^ vx1) << 3)];
                O1 = __builtin_amdgcn_mfma_f32_32x32x16_bf16(vfb, pfb1, O1, 0, 0, 0);
            }
        }

        // ---- publish next pair; retire this window's reads ----
        if (p < NPAIRS - 1) BAR();
    }

    // ---- epilogue: combine s-halves (partner waves), normalize, store O^T ----
    l += __shfl_xor(l, 32);              // add other lane-half's s-contribution

    __syncthreads();                     // all PV reads retired; repurpose LDS
    float* xo = (float*)smem;            // 4 groups x 8KB partial-O exchange (kp0/kp1)
    float* xl = (float*)(smem + 32768);  // l exchange (vp0; last window read vp1)
    if (sh == 1) {
        float* b = xo + g * 2048;
        #pragma unroll
        for (int rq = 0; rq < 4; ++rq) {
            floatx4 a0 = {O0[4 * rq], O0[4 * rq + 1], O0[4 * rq + 2], O0[4 * rq + 3]};
            *(floatx4*)&b[(rq * 64 + lane) * 4] = a0;
            floatx4 a1 = {O1[4 * rq], O1[4 * rq + 1], O1[4 * rq + 2], O1[4 * rq + 3]};
            *(floatx4*)&b[((4 + rq) * 64 + lane) * 4] = a1;
        }
        xl[g * 64 + lane] = l;
    }
    __syncthreads();
    if (sh == 0) {
        const float* b = xo + g * 2048;
        const float lt = l + xl[g * 64 + lane];
        const float linv = 1.0f / lt;
        float* og = out + (size_t)bh * 65536 + t0 + g * 32;
        #pragma unroll
        for (int rq = 0; rq < 4; ++rq) {
            floatx4 a0 = *(const floatx4*)&b[(rq * 64 + lane) * 4];
            floatx4 a1 = *(const floatx4*)&b[((4 + rq) * 64 + lane) * 4];
            #pragma unroll
            for (int j = 0; j < 4; ++j) {
                int cl = j + 8 * rq + 4 * hv;       // C-layout row within c-tile
                og[cl * 1024 + l31] = (O0[4 * rq + j] + a0[j]) * linv;
                og[(32 + cl) * 1024 + l31] = (O1[4 * rq + j] + a1[j]) * linv;
            }
        }
    }
}

extern "C" void kernel_launch(void* const* d_in, const int* in_sizes, int n_in,
                              void* d_out, int out_size, void* d_ws, size_t ws_size,
                              hipStream_t stream) {
    const float* qkv = (const float*)d_in[0];
    float* out = (float*)d_out;
    attn_kernel<<<dim3(512), dim3(NTHREADS), 0, stream>>>(qkv, out);
}